// Round 8
// baseline (861.827 us; speedup 1.0000x reference)
//
#include <hip/hip_runtime.h>
#include <hip/hip_fp16.h>

constexpr int N  = 50000;
constexpr int E  = 1600000;
constexpr int T  = 8;
constexpr int H  = 64;
constexpr int C  = 10;
constexpr int CSR_CAP = E + 8 * N + 64;   // padded rows + prefetch slack

// ---------------- degree + histogram ----------------
__global__ void deg_count_kernel(const int* __restrict__ ei, const float* __restrict__ w,
                                 float* __restrict__ deg, int* __restrict__ counts) {
  int e = blockIdx.x * blockDim.x + threadIdx.x;
  if (e >= E) return;
  int d = ei[E + e];
  atomicAdd(&deg[d], w[e]);
  atomicAdd(&counts[d], 1);
}

__global__ void dinv_kernel(float* deg) {
  int n = blockIdx.x * blockDim.x + threadIdx.x;
  if (n >= N) return;
  deg[n] = rsqrtf(deg[n] + 1.0f);  // +1 = self-loop weight
}

// ---------------- two-level scan over PADDED counts: (c+1) rounded up to 8 ----------------
__global__ void scanA_kernel(const int* __restrict__ counts, int* __restrict__ rowptr,
                             int* __restrict__ bsum) {
  __shared__ int ws[4];
  int b = blockIdx.x, t = threadIdx.x;
  int base = b * 1024 + t * 4;
  auto pad8 = [](int c) { return (c + 8) & ~7; };   // ceil((c+1)/8)*8
  int v0 = (base + 0 < N) ? pad8(counts[base + 0]) : 0;
  int v1 = (base + 1 < N) ? pad8(counts[base + 1]) : 0;
  int v2 = (base + 2 < N) ? pad8(counts[base + 2]) : 0;
  int v3 = (base + 3 < N) ? pad8(counts[base + 3]) : 0;
  int s = v0 + v1 + v2 + v3;
  int lane = t & 63, wid = t >> 6;
  int x = s;
  #pragma unroll
  for (int off = 1; off < 64; off <<= 1) {
    int y = __shfl_up(x, off, 64);
    if (lane >= off) x += y;
  }
  if (lane == 63) ws[wid] = x;
  __syncthreads();
  int woff = 0;
  #pragma unroll
  for (int k = 0; k < 4; ++k) if (k < wid) woff += ws[k];
  int a = x + woff - s;   // exclusive prefix within tile
  a += v0; if (base + 0 < N) rowptr[base + 1] = a;
  a += v1; if (base + 1 < N) rowptr[base + 2] = a;
  a += v2; if (base + 2 < N) rowptr[base + 3] = a;
  a += v3; if (base + 3 < N) rowptr[base + 4] = a;
  if (t == 255) bsum[b] = x + woff;   // tile total
}

__global__ void scanB_kernel(const int* __restrict__ bsum, int* __restrict__ boff, int nb) {
  int t = threadIdx.x;   // 64 threads
  int v = (t < nb) ? bsum[t] : 0;
  int x = v;
  #pragma unroll
  for (int off = 1; off < 64; off <<= 1) {
    int y = __shfl_up(x, off, 64);
    if (t >= off) x += y;
  }
  if (t < nb) boff[t] = x - v;   // exclusive
}

__global__ void scanC_kernel(int* __restrict__ rowptr, const int* __restrict__ boff) {
  int i = blockIdx.x * 256 + threadIdx.x;
  if (i == 0) rowptr[0] = 0;
  if (i < N) rowptr[i + 1] += boff[i >> 10];
}

// ---------------- self-loop + zero-weight pad entries ----------------
__global__ void self_pad_kernel(const int* __restrict__ counts, const int* __restrict__ rowptr,
                                const float* __restrict__ dinv, int* __restrict__ csr_src,
                                __half* __restrict__ csr_nrmh) {
  int n = blockIdx.x * 256 + threadIdx.x;
  if (n >= N) return;
  int base = rowptr[n], end = rowptr[n + 1];
  float di = dinv[n];
  csr_src[base] = n;
  csr_nrmh[base] = __float2half_rn(di * di);
  for (int i = base + 1 + counts[n]; i < end; ++i) {
    csr_src[i] = n;
    csr_nrmh[i] = __float2half_rn(0.f);
  }
}

// ---------------- CSR fill (edges go after the self slot) ----------------
__global__ void fill_kernel(const int* __restrict__ ei, const float* __restrict__ w,
                            const float* __restrict__ dinv, const int* __restrict__ rowptr,
                            int* __restrict__ fill, int* __restrict__ csr_src,
                            __half* __restrict__ csr_nrmh) {
  int e = blockIdx.x * blockDim.x + threadIdx.x;
  if (e >= E) return;
  int s = ei[e], d = ei[E + e];
  int pos = rowptr[d] + 1 + atomicAdd(&fill[d], 1);
  csr_src[pos] = s;
  csr_nrmh[pos] = __float2half_rn(dinv[s] * w[e] * dinv[d]);
}

// ---------------- x (fp32) -> xh (fp16) ----------------
__global__ void cvt_x_kernel(const float* __restrict__ x, __half* __restrict__ xh) {
  int i = blockIdx.x * blockDim.x + threadIdx.x;  // over N*32 float4s
  if (i >= N * 32) return;
  float4 v = ((const float4*)x)[i];
  __half2 h0; h0.x = __float2half_rn(v.x); h0.y = __float2half_rn(v.y);
  __half2 h1; h1.x = __float2half_rn(v.z); h1.y = __float2half_rn(v.w);
  uint2 u;
  u.x = __builtin_bit_cast(unsigned int, h0);
  u.y = __builtin_bit_cast(unsigned int, h1);
  ((uint2*)xh)[i] = u;
}

// 8-halves fused accumulate helper
__device__ __forceinline__ void accum8(float* acc, uint4 r, float wgt) {
  float2 f0 = __half22float2(__builtin_bit_cast(__half2, r.x));
  float2 f1 = __half22float2(__builtin_bit_cast(__half2, r.y));
  float2 f2 = __half22float2(__builtin_bit_cast(__half2, r.z));
  float2 f3 = __half22float2(__builtin_bit_cast(__half2, r.w));
  acc[0] = fmaf(wgt, f0.x, acc[0]); acc[1] = fmaf(wgt, f0.y, acc[1]);
  acc[2] = fmaf(wgt, f1.x, acc[2]); acc[3] = fmaf(wgt, f1.y, acc[3]);
  acc[4] = fmaf(wgt, f2.x, acc[4]); acc[5] = fmaf(wgt, f2.y, acc[5]);
  acc[6] = fmaf(wgt, f3.x, acc[6]); acc[7] = fmaf(wgt, f3.y, acc[7]);
}

// ---------------- xagg = Ahat @ X, fp16 256B rows; branchless, 8 rows in flight ----------------
__global__ void agg_x_kernel(const __half* __restrict__ xh, const int* __restrict__ rowptr,
                             const int* __restrict__ csr_src, const __half* __restrict__ csr_nrmh,
                             float* __restrict__ xagg) {
  int tid = threadIdx.x;
  int w = tid >> 6, l = tid & 63;
  int sub = l >> 4, q = l & 15;      // 4 groups x 16 lanes; lane covers 16B of 256B row
  int n = blockIdx.x * 4 + w;
  int e0 = rowptr[n], cnt = rowptr[n + 1] - e0;   // cnt % 8 == 0, >= 8
  float acc[8] = {0, 0, 0, 0, 0, 0, 0, 0};
  int   sA = csr_src[e0 + sub],      sB = csr_src[e0 + sub + 4];
  float wA = __half2float(csr_nrmh[e0 + sub]);
  float wB = __half2float(csr_nrmh[e0 + sub + 4]);
  for (int i = sub; i < cnt; i += 8) {
    uint4 rA = *reinterpret_cast<const uint4*>(xh + (size_t)sA * 128 + q * 8);
    uint4 rB = *reinterpret_cast<const uint4*>(xh + (size_t)sB * 128 + q * 8);
    float uA = wA, uB = wB;
    int j = e0 + i + 8;                 // prefetch (slack-covered past row end)
    sA = csr_src[j];     wA = __half2float(csr_nrmh[j]);
    sB = csr_src[j + 4]; wB = __half2float(csr_nrmh[j + 4]);
    accum8(acc, rA, uA);
    accum8(acc, rB, uB);
  }
  #pragma unroll
  for (int v = 0; v < 8; ++v) {
    acc[v] += __shfl_xor(acc[v], 16, 64);
    acc[v] += __shfl_xor(acc[v], 32, 64);
  }
  if (sub == 0) {
    float4 o0; o0.x = acc[0]; o0.y = acc[1]; o0.z = acc[2]; o0.w = acc[3];
    float4 o1; o1.x = acc[4]; o1.y = acc[5]; o1.z = acc[6]; o1.w = acc[7];
    float4* dst = (float4*)(xagg + (size_t)n * 128 + q * 8);
    dst[0] = o0; dst[1] = o1;
  }
}

// ---------------- dense: h1 = relu(xagg_t @ W1 + b1); G2 = h1 @ W2 (fp16, all t) ----------------
__global__ void dense12_kernel(const float* __restrict__ xagg, const float* __restrict__ W1,
                               const float* __restrict__ b1, const float* __restrict__ W2,
                               __half* __restrict__ G2h) {
  __shared__ float xs[4 * 128];
  __shared__ float h1s[4][8][64];
  int tid = threadIdx.x;
  int n0 = blockIdx.x * 4;
  ((float2*)xs)[tid] = ((const float2*)(xagg + (size_t)n0 * 128))[tid];
  __syncthreads();
  int nb = tid >> 6, j = tid & 63;
  float a[8];
  float bj = b1[j];
  #pragma unroll
  for (int t = 0; t < 8; ++t) a[t] = bj;
  for (int f = 0; f < 16; ++f) {
    float wv = W1[f * 64 + j];
    #pragma unroll
    for (int t = 0; t < 8; ++t) a[t] = fmaf(xs[nb * 128 + f * 8 + t], wv, a[t]);
  }
  #pragma unroll
  for (int t = 0; t < 8; ++t) h1s[nb][t][j] = fmaxf(a[t], 0.f);
  __syncthreads();
  float g[8];
  #pragma unroll
  for (int t = 0; t < 8; ++t) g[t] = 0.f;
  for (int k = 0; k < 64; ++k) {
    float wv = W2[k * 64 + j];
    #pragma unroll
    for (int t = 0; t < 8; ++t) g[t] = fmaf(h1s[nb][t][k], wv, g[t]);
  }
  __half* gp = G2h + (size_t)(n0 + nb) * 512 + j;
  #pragma unroll
  for (int t = 0; t < 8; ++t) gp[t * 64] = __float2half_rn(g[t]);
}

// ---------------- conv2: branchless 4-deep aggregate; h2=relu(+b2); G3h = h2 @ W3 ----------------
__global__ void conv2w_kernel(const __half* __restrict__ G2h, const int* __restrict__ rowptr,
                              const int* __restrict__ csr_src, const __half* __restrict__ csr_nrmh,
                              const float* __restrict__ b2,
                              const float* __restrict__ W3, __half* __restrict__ G3h) {
  __shared__ float h2s[4][512];
  int tid = threadIdx.x;
  int w = tid >> 6, l = tid & 63;
  int n0 = blockIdx.x * 4;
  int n = n0 + w;
  int e0 = rowptr[n], cnt = rowptr[n + 1] - e0;   // cnt % 8 == 0
  float acc[8] = {0, 0, 0, 0, 0, 0, 0, 0};
  int sm[4]; float wm[4];
  #pragma unroll
  for (int q = 0; q < 4; ++q) {
    sm[q] = csr_src[e0 + q];
    wm[q] = __half2float(csr_nrmh[e0 + q]);
  }
  for (int i = 0; i < cnt; i += 4) {
    uint4 r0 = *reinterpret_cast<const uint4*>(G2h + (size_t)sm[0] * 512 + l * 8);
    uint4 r1 = *reinterpret_cast<const uint4*>(G2h + (size_t)sm[1] * 512 + l * 8);
    uint4 r2 = *reinterpret_cast<const uint4*>(G2h + (size_t)sm[2] * 512 + l * 8);
    uint4 r3 = *reinterpret_cast<const uint4*>(G2h + (size_t)sm[3] * 512 + l * 8);
    float w0 = wm[0], w1 = wm[1], w2 = wm[2], w3 = wm[3];
    #pragma unroll
    for (int q = 0; q < 4; ++q) {
      int j = e0 + i + 4 + q;          // slack-covered prefetch
      sm[q] = csr_src[j];
      wm[q] = __half2float(csr_nrmh[j]);
    }
    accum8(acc, r0, w0);
    accum8(acc, r1, w1);
    accum8(acc, r2, w2);
    accum8(acc, r3, w3);
  }
  #pragma unroll
  for (int q = 0; q < 8; ++q)
    h2s[w][l * 8 + q] = fmaxf(acc[q] + b2[(l * 8 + q) & 63], 0.f);
  __syncthreads();
  // per-t dense: G3[t*64 + j] = sum_k h2[t*64+k] * W3[k][j]
  int t = tid >> 5;            // 0..7
  int jh = tid & 31, j0 = 2 * jh;
  float g[4][2];
  #pragma unroll
  for (int q = 0; q < 4; ++q) { g[q][0] = 0.f; g[q][1] = 0.f; }
  const float2* W3v = (const float2*)W3;
  for (int k = 0; k < 64; ++k) {
    float2 wv = W3v[k * 32 + jh];
    #pragma unroll
    for (int q = 0; q < 4; ++q) {
      float h = h2s[q][t * 64 + k];
      g[q][0] = fmaf(h, wv.x, g[q][0]);
      g[q][1] = fmaf(h, wv.y, g[q][1]);
    }
  }
  #pragma unroll
  for (int q = 0; q < 4; ++q) {
    __half2 hv;
    hv.x = __float2half_rn(g[q][0]);
    hv.y = __float2half_rn(g[q][1]);
    *reinterpret_cast<__half2*>(G3h + (size_t)(n0 + q) * 512 + t * 64 + j0) = hv;
  }
}

// ---------------- conv3 + head: branchless 4-deep; h3=relu(+b3); out = relu(h3@Wseq+bseq)@Wcls+bcls ----------------
__global__ void conv3w_kernel(const __half* __restrict__ G3h, const int* __restrict__ rowptr,
                              const int* __restrict__ csr_src, const __half* __restrict__ csr_nrmh,
                              const float* __restrict__ b3,
                              const float* __restrict__ Wseq, const float* __restrict__ bseq,
                              const float* __restrict__ Wcls, const float* __restrict__ bcls,
                              float* __restrict__ out) {
  __shared__ float h3s[4][512];
  __shared__ float red[4][4][64];
  __shared__ float hfs[4][64];
  int tid = threadIdx.x;
  int w = tid >> 6, l = tid & 63;
  int n0 = blockIdx.x * 4;
  int n = n0 + w;
  int e0 = rowptr[n], cnt = rowptr[n + 1] - e0;
  float acc[8] = {0, 0, 0, 0, 0, 0, 0, 0};
  int sm[4]; float wm[4];
  #pragma unroll
  for (int q = 0; q < 4; ++q) {
    sm[q] = csr_src[e0 + q];
    wm[q] = __half2float(csr_nrmh[e0 + q]);
  }
  for (int i = 0; i < cnt; i += 4) {
    uint4 r0 = *reinterpret_cast<const uint4*>(G3h + (size_t)sm[0] * 512 + l * 8);
    uint4 r1 = *reinterpret_cast<const uint4*>(G3h + (size_t)sm[1] * 512 + l * 8);
    uint4 r2 = *reinterpret_cast<const uint4*>(G3h + (size_t)sm[2] * 512 + l * 8);
    uint4 r3 = *reinterpret_cast<const uint4*>(G3h + (size_t)sm[3] * 512 + l * 8);
    float w0 = wm[0], w1 = wm[1], w2 = wm[2], w3 = wm[3];
    #pragma unroll
    for (int q = 0; q < 4; ++q) {
      int j = e0 + i + 4 + q;
      sm[q] = csr_src[j];
      wm[q] = __half2float(csr_nrmh[j]);
    }
    accum8(acc, r0, w0);
    accum8(acc, r1, w1);
    accum8(acc, r2, w2);
    accum8(acc, r3, w3);
  }
  #pragma unroll
  for (int q = 0; q < 8; ++q)
    h3s[w][l * 8 + q] = fmaxf(acc[q] + b3[(l * 8 + q) & 63], 0.f);
  __syncthreads();
  // seq contraction: partial[p][nb][j] = sum_{c in p-range} h3[nb][c] * Wseq[c][j]
  int p = tid >> 6, j = tid & 63;
  float pa0 = 0.f, pa1 = 0.f, pa2 = 0.f, pa3 = 0.f;
  for (int ci = 0; ci < 128; ++ci) {
    int c = p * 128 + ci;
    float wv = Wseq[(size_t)c * 64 + j];
    pa0 = fmaf(h3s[0][c], wv, pa0);
    pa1 = fmaf(h3s[1][c], wv, pa1);
    pa2 = fmaf(h3s[2][c], wv, pa2);
    pa3 = fmaf(h3s[3][c], wv, pa3);
  }
  red[p][0][j] = pa0; red[p][1][j] = pa1; red[p][2][j] = pa2; red[p][3][j] = pa3;
  __syncthreads();
  int nb = tid >> 6, k = tid & 63;
  float s = red[0][nb][k] + red[1][nb][k] + red[2][nb][k] + red[3][nb][k] + bseq[k];
  hfs[nb][k] = fmaxf(s, 0.f);
  __syncthreads();
  if (k < C) {
    float o = bcls[k];
    #pragma unroll
    for (int kk = 0; kk < 64; ++kk) o = fmaf(hfs[nb][kk], Wcls[kk * C + k], o);
    out[(size_t)(n0 + nb) * C + k] = o;
  }
}

// ================= NARROW FALLBACK (fp32, per-t, padded CSR) =================
__global__ void layer1N_kernel(const float* __restrict__ xagg, const float* __restrict__ W1,
                               const float* __restrict__ b1, const float* __restrict__ W2,
                               float* __restrict__ GA, int t) {
  __shared__ float hs[4][H];
  int tid = threadIdx.x;
  int wv = tid >> 6, j = tid & 63;
  int n = blockIdx.x * 4 + wv;
  const float* xa = xagg + (size_t)n * 128;
  float a = b1[j];
  #pragma unroll
  for (int f = 0; f < 16; ++f) a += xa[f * 8 + t] * W1[f * H + j];
  hs[wv][j] = fmaxf(a, 0.f);
  __syncthreads();
  float g = 0.f;
  #pragma unroll
  for (int k = 0; k < H; ++k) g += hs[wv][k] * W2[k * H + j];
  GA[(size_t)n * H + j] = g;
}

template<bool ACCUM>
__global__ void convN_kernel(const float* __restrict__ Gin, const int* __restrict__ rowptr,
                             const int* __restrict__ csr_src, const __half* __restrict__ csr_nrmh,
                             const float* __restrict__ b,
                             const float* __restrict__ Wnext, float* __restrict__ Gout) {
  __shared__ __align__(16) float hs[4][H];
  int tid = threadIdx.x;
  int wv = tid >> 6, lane = tid & 63;
  int sub = lane >> 4, q = lane & 15;
  int n = blockIdx.x * 4 + wv;
  const float4* G4 = (const float4*)Gin;
  float4 a0 = {0,0,0,0};
  int e0 = rowptr[n], e1 = rowptr[n + 1];
  for (int e = e0 + sub; e < e1; e += 4) {
    int s0 = csr_src[e];
    float w0 = __half2float(csr_nrmh[e]);
    float4 r0 = G4[(size_t)s0 * 16 + q];
    a0.x += w0 * r0.x; a0.y += w0 * r0.y; a0.z += w0 * r0.z; a0.w += w0 * r0.w;
  }
  #pragma unroll
  for (int off = 16; off <= 32; off <<= 1) {
    a0.x += __shfl_xor(a0.x, off, 64);
    a0.y += __shfl_xor(a0.y, off, 64);
    a0.z += __shfl_xor(a0.z, off, 64);
    a0.w += __shfl_xor(a0.w, off, 64);
  }
  if (sub == 0) {
    float4 h;
    h.x = fmaxf(a0.x + b[4 * q + 0], 0.f);
    h.y = fmaxf(a0.y + b[4 * q + 1], 0.f);
    h.z = fmaxf(a0.z + b[4 * q + 2], 0.f);
    h.w = fmaxf(a0.w + b[4 * q + 3], 0.f);
    ((float4*)hs[wv])[q] = h;
  }
  __syncthreads();
  float g = 0.f;
  #pragma unroll
  for (int k = 0; k < H; ++k) g += hs[wv][k] * Wnext[k * H + lane];
  if (ACCUM) Gout[(size_t)n * H + lane] += g;
  else       Gout[(size_t)n * H + lane]  = g;
}

__global__ void final_kernel(const float* __restrict__ acc, const float* __restrict__ bseq,
                             const float* __restrict__ Wcls, const float* __restrict__ bcls,
                             float* __restrict__ out) {
  __shared__ float hs[4][H];
  int tid = threadIdx.x;
  int wv = tid >> 6, j = tid & 63;
  int n = blockIdx.x * 4 + wv;
  hs[wv][j] = fmaxf(acc[(size_t)n * H + j] + bseq[j], 0.0f);
  __syncthreads();
  if (j < C) {
    float o = bcls[j];
    #pragma unroll
    for (int k = 0; k < H; ++k) o += hs[wv][k] * Wcls[k * C + j];
    out[(size_t)n * C + j] = o;
  }
}

extern "C" void kernel_launch(void* const* d_in, const int* in_sizes, int n_in,
                              void* d_out, int out_size, void* d_ws, size_t ws_size,
                              hipStream_t stream) {
  const float* x    = (const float*)d_in[0];
  const int*   ei   = (const int*)  d_in[1];
  const float* w    = (const float*)d_in[2];
  const float* W1   = (const float*)d_in[3];
  const float* b1   = (const float*)d_in[4];
  const float* W2   = (const float*)d_in[5];
  const float* b2   = (const float*)d_in[6];
  const float* W3   = (const float*)d_in[7];
  const float* b3   = (const float*)d_in[8];
  const float* Wseq = (const float*)d_in[9];
  const float* bseq = (const float*)d_in[10];
  const float* Wcls = (const float*)d_in[11];
  const float* bcls = (const float*)d_in[12];
  float* out = (float*)d_out;

  char* p = (char*)d_ws;
  auto alloc = [&](size_t bytes) -> char* {
    char* r = p; p += (bytes + 255) & ~(size_t)255; return r;
  };
  float*  deg     = (float*) alloc((size_t)N * 4);      // becomes dinv
  int*    counts  = (int*)   alloc((size_t)N * 4);
  int*    fillc   = (int*)   alloc((size_t)N * 4);
  int*    rowptr  = (int*)   alloc((size_t)(N + 1) * 4);
  int*    bsum    = (int*)   alloc(64 * 4);
  int*    boff    = (int*)   alloc(64 * 4);
  int*    csr_src = (int*)   alloc((size_t)CSR_CAP * 4);
  __half* csr_nrmh= (__half*)alloc((size_t)CSR_CAP * 2);
  float*  xagg    = (float*) alloc((size_t)N * 128 * 4);
  __half* xh      = (__half*)alloc((size_t)N * 128 * 2);

  hipMemsetAsync(deg,    0, (size_t)N * 4, stream);
  hipMemsetAsync(counts, 0, (size_t)N * 4, stream);
  hipMemsetAsync(fillc,  0, (size_t)N * 4, stream);

  constexpr int NTILES = (N + 1023) / 1024;   // 49
  cvt_x_kernel<<<(N * 32 + 255) / 256, 256, 0, stream>>>(x, xh);
  deg_count_kernel<<<(E + 255) / 256, 256, 0, stream>>>(ei, w, deg, counts);
  dinv_kernel<<<(N + 255) / 256, 256, 0, stream>>>(deg);
  scanA_kernel<<<NTILES, 256, 0, stream>>>(counts, rowptr, bsum);
  scanB_kernel<<<1, 64, 0, stream>>>(bsum, boff, NTILES);
  scanC_kernel<<<(N + 255) / 256, 256, 0, stream>>>(rowptr, boff);
  self_pad_kernel<<<(N + 255) / 256, 256, 0, stream>>>(counts, rowptr, deg, csr_src, csr_nrmh);
  fill_kernel<<<(E + 255) / 256, 256, 0, stream>>>(ei, w, deg, rowptr, fillc, csr_src, csr_nrmh);
  agg_x_kernel<<<N / 4, 256, 0, stream>>>(xh, rowptr, csr_src, csr_nrmh, xagg);

  // wide needs: common ~50.8MB + G2h 51.2MB + G3h 51.2MB ~= 153.8MB
  bool wide = ws_size >= (size_t)155 * 1000 * 1000;

  if (wide) {
    __half* G2h = (__half*)alloc((size_t)N * 512 * 2);
    __half* G3h = (__half*)alloc((size_t)N * 512 * 2);
    dense12_kernel<<<N / 4, 256, 0, stream>>>(xagg, W1, b1, W2, G2h);
    conv2w_kernel<<<N / 4, 256, 0, stream>>>(G2h, rowptr, csr_src, csr_nrmh, b2, W3, G3h);
    conv3w_kernel<<<N / 4, 256, 0, stream>>>(G3h, rowptr, csr_src, csr_nrmh, b3,
                                             Wseq, bseq, Wcls, bcls, out);
  } else {
    float* GA  = (float*)alloc((size_t)N * H * 4);
    float* GB  = (float*)alloc((size_t)N * H * 4);
    float* acc = (float*)alloc((size_t)N * H * 4);
    hipMemsetAsync(acc, 0, (size_t)N * H * 4, stream);
    for (int t = 0; t < T; ++t) {
      layer1N_kernel<<<N / 4, 256, 0, stream>>>(xagg, W1, b1, W2, GA, t);
      convN_kernel<false><<<N / 4, 256, 0, stream>>>(GA, rowptr, csr_src, csr_nrmh, b2, W3, GB);
      convN_kernel<true ><<<N / 4, 256, 0, stream>>>(GB, rowptr, csr_src, csr_nrmh, b3,
                                                     Wseq + (size_t)t * H * H, acc);
    }
    final_kernel<<<N / 4, 256, 0, stream>>>(acc, bseq, Wcls, bcls, out);
  }
}

// Round 9
// 856.889 us; speedup vs baseline: 1.0058x; 1.0058x over previous
//
#include <hip/hip_runtime.h>
#include <hip/hip_fp16.h>

constexpr int N  = 50000;
constexpr int E  = 1600000;
constexpr int T  = 8;
constexpr int H  = 64;
constexpr int C  = 10;

// ---------------- degree + histogram ----------------
__global__ void deg_count_kernel(const int* __restrict__ ei, const float* __restrict__ w,
                                 float* __restrict__ deg, int* __restrict__ counts) {
  int e = blockIdx.x * blockDim.x + threadIdx.x;
  if (e >= E) return;
  int d = ei[E + e];
  atomicAdd(&deg[d], w[e]);
  atomicAdd(&counts[d], 1);
}

__global__ void dinv_kernel(float* deg) {
  int n = blockIdx.x * blockDim.x + threadIdx.x;
  if (n >= N) return;
  deg[n] = rsqrtf(deg[n] + 1.0f);  // +1 = self-loop weight
}

// ---------------- two-level scan: A (per-1024-tile), B (tile sums), C (add offsets) ----------------
__global__ void scanA_kernel(const int* __restrict__ counts, int* __restrict__ rowptr,
                             int* __restrict__ bsum) {
  __shared__ int ws[4];
  int b = blockIdx.x, t = threadIdx.x;
  int base = b * 1024 + t * 4;
  int v0 = (base + 0 < N) ? counts[base + 0] : 0;
  int v1 = (base + 1 < N) ? counts[base + 1] : 0;
  int v2 = (base + 2 < N) ? counts[base + 2] : 0;
  int v3 = (base + 3 < N) ? counts[base + 3] : 0;
  int s = v0 + v1 + v2 + v3;
  int lane = t & 63, wid = t >> 6;
  int x = s;
  #pragma unroll
  for (int off = 1; off < 64; off <<= 1) {
    int y = __shfl_up(x, off, 64);
    if (lane >= off) x += y;
  }
  if (lane == 63) ws[wid] = x;
  __syncthreads();
  int woff = 0;
  #pragma unroll
  for (int k = 0; k < 4; ++k) if (k < wid) woff += ws[k];
  int a = x + woff - s;   // exclusive prefix within tile
  a += v0; if (base + 0 < N) rowptr[base + 1] = a;
  a += v1; if (base + 1 < N) rowptr[base + 2] = a;
  a += v2; if (base + 2 < N) rowptr[base + 3] = a;
  a += v3; if (base + 3 < N) rowptr[base + 4] = a;
  if (t == 255) bsum[b] = x + woff;   // tile total
}

__global__ void scanB_kernel(const int* __restrict__ bsum, int* __restrict__ boff, int nb) {
  int t = threadIdx.x;   // 64 threads
  int v = (t < nb) ? bsum[t] : 0;
  int x = v;
  #pragma unroll
  for (int off = 1; off < 64; off <<= 1) {
    int y = __shfl_up(x, off, 64);
    if (t >= off) x += y;
  }
  if (t < nb) boff[t] = x - v;   // exclusive
}

__global__ void scanC_kernel(int* __restrict__ rowptr, const int* __restrict__ boff) {
  int i = blockIdx.x * 256 + threadIdx.x;
  if (i == 0) rowptr[0] = 0;
  if (i < N) rowptr[i + 1] += boff[i >> 10];
}

// ---------------- CSR fill (split arrays — wave-uniform scalar loads in gathers) ----------------
__global__ void fill_kernel(const int* __restrict__ ei, const float* __restrict__ w,
                            const float* __restrict__ dinv, const int* __restrict__ rowptr,
                            int* __restrict__ fill, int* __restrict__ csr_src,
                            float* __restrict__ csr_norm) {
  int e = blockIdx.x * blockDim.x + threadIdx.x;
  if (e >= E) return;
  int s = ei[e], d = ei[E + e];
  int pos = rowptr[d] + atomicAdd(&fill[d], 1);
  csr_src[pos] = s;
  csr_norm[pos] = dinv[s] * w[e] * dinv[d];
}

// ---------------- x (fp32) -> xh (fp16) ----------------
__global__ void cvt_x_kernel(const float* __restrict__ x, __half* __restrict__ xh) {
  int i = blockIdx.x * blockDim.x + threadIdx.x;  // over N*32 float4s
  if (i >= N * 32) return;
  float4 v = ((const float4*)x)[i];
  __half2 h0; h0.x = __float2half_rn(v.x); h0.y = __float2half_rn(v.y);
  __half2 h1; h1.x = __float2half_rn(v.z); h1.y = __float2half_rn(v.w);
  uint2 u;
  u.x = __builtin_bit_cast(unsigned int, h0);
  u.y = __builtin_bit_cast(unsigned int, h1);
  ((uint2*)xh)[i] = u;
}

// 8-halves fused accumulate helper
__device__ __forceinline__ void accum8(float* acc, uint4 r, float wgt) {
  float2 f0 = __half22float2(__builtin_bit_cast(__half2, r.x));
  float2 f1 = __half22float2(__builtin_bit_cast(__half2, r.y));
  float2 f2 = __half22float2(__builtin_bit_cast(__half2, r.z));
  float2 f3 = __half22float2(__builtin_bit_cast(__half2, r.w));
  acc[0] = fmaf(wgt, f0.x, acc[0]); acc[1] = fmaf(wgt, f0.y, acc[1]);
  acc[2] = fmaf(wgt, f1.x, acc[2]); acc[3] = fmaf(wgt, f1.y, acc[3]);
  acc[4] = fmaf(wgt, f2.x, acc[4]); acc[5] = fmaf(wgt, f2.y, acc[5]);
  acc[6] = fmaf(wgt, f3.x, acc[6]); acc[7] = fmaf(wgt, f3.y, acc[7]);
}

// ---------------- xagg = Ahat @ X, fp16 256B rows; 4 groups x 2-deep = 8 rows in flight ----------------
__global__ void agg_x_kernel(const __half* __restrict__ xh, const float* __restrict__ dinv,
                             const int* __restrict__ rowptr, const int* __restrict__ csr_src,
                             const float* __restrict__ csr_norm, float* __restrict__ xagg) {
  int tid = threadIdx.x;
  int w = tid >> 6, l = tid & 63;
  int sub = l >> 4, q = l & 15;      // 4 groups x 16 lanes; lane covers 16B of 256B row
  int n = blockIdx.x * 4 + w;
  float di = dinv[n], dd = di * di;
  int e0 = rowptr[n], e1 = rowptr[n + 1];
  int cnt = e1 - e0 + 1;             // item 0 = self
  float acc[8] = {0, 0, 0, 0, 0, 0, 0, 0};
  int sA, sB; float wA, wB;
  auto meta = [&](int idx, int& s_, float& w_) {
    if (idx == 0)       { s_ = n; w_ = dd; }
    else if (idx < cnt) { s_ = csr_src[e0 + idx - 1]; w_ = csr_norm[e0 + idx - 1]; }
    else                { s_ = n; w_ = 0.f; }
  };
  meta(sub,     sA, wA);
  meta(sub + 4, sB, wB);
  for (int i = sub; i < cnt; i += 8) {
    uint4 rA = *reinterpret_cast<const uint4*>(xh + (size_t)sA * 128 + q * 8);
    uint4 rB = *reinterpret_cast<const uint4*>(xh + (size_t)sB * 128 + q * 8);
    float uA = wA, uB = wB;
    meta(i + 8,  sA, wA);
    meta(i + 12, sB, wB);
    accum8(acc, rA, uA);
    accum8(acc, rB, uB);
  }
  #pragma unroll
  for (int v = 0; v < 8; ++v) {
    acc[v] += __shfl_xor(acc[v], 16, 64);
    acc[v] += __shfl_xor(acc[v], 32, 64);
  }
  if (sub == 0) {
    float4 o0; o0.x = acc[0]; o0.y = acc[1]; o0.z = acc[2]; o0.w = acc[3];
    float4 o1; o1.x = acc[4]; o1.y = acc[5]; o1.z = acc[6]; o1.w = acc[7];
    float4* dst = (float4*)(xagg + (size_t)n * 128 + q * 8);
    dst[0] = o0; dst[1] = o1;
  }
}

// ---------------- dense: h1 = relu(xagg_t @ W1 + b1); G2 = h1 @ W2 (fp16, all t) ----------------
__global__ void dense12_kernel(const float* __restrict__ xagg, const float* __restrict__ W1,
                               const float* __restrict__ b1, const float* __restrict__ W2,
                               __half* __restrict__ G2h) {
  __shared__ float xs[4 * 128];
  __shared__ float h1s[4][8][64];
  int tid = threadIdx.x;
  int n0 = blockIdx.x * 4;
  ((float2*)xs)[tid] = ((const float2*)(xagg + (size_t)n0 * 128))[tid];
  __syncthreads();
  int nb = tid >> 6, j = tid & 63;
  float a[8];
  float bj = b1[j];
  #pragma unroll
  for (int t = 0; t < 8; ++t) a[t] = bj;
  for (int f = 0; f < 16; ++f) {
    float wv = W1[f * 64 + j];
    #pragma unroll
    for (int t = 0; t < 8; ++t) a[t] = fmaf(xs[nb * 128 + f * 8 + t], wv, a[t]);
  }
  #pragma unroll
  for (int t = 0; t < 8; ++t) h1s[nb][t][j] = fmaxf(a[t], 0.f);
  __syncthreads();
  float g[8];
  #pragma unroll
  for (int t = 0; t < 8; ++t) g[t] = 0.f;
  for (int k = 0; k < 64; ++k) {
    float wv = W2[k * 64 + j];
    #pragma unroll
    for (int t = 0; t < 8; ++t) g[t] = fmaf(h1s[nb][t][k], wv, g[t]);
  }
  __half* gp = G2h + (size_t)(n0 + nb) * 512 + j;
  #pragma unroll
  for (int t = 0; t < 8; ++t) gp[t * 64] = __float2half_rn(g[t]);
}

// ---------------- conv2: aggregate G2h (1KB fp16 rows, 8-deep); h2=relu(+b2); G3h = h2 @ W3 ----------------
__global__ void conv2w_kernel(const __half* __restrict__ G2h, const float* __restrict__ dinv,
                              const int* __restrict__ rowptr, const int* __restrict__ csr_src,
                              const float* __restrict__ csr_norm, const float* __restrict__ b2,
                              const float* __restrict__ W3, __half* __restrict__ G3h) {
  __shared__ float h2s[4][512];
  int tid = threadIdx.x;
  int w = tid >> 6, l = tid & 63;
  int n0 = blockIdx.x * 4;
  int n = n0 + w;
  float di = dinv[n], dd = di * di;
  int e0 = rowptr[n], e1 = rowptr[n + 1];
  int cnt = e1 - e0 + 1;             // item 0 = self
  float acc[8] = {0, 0, 0, 0, 0, 0, 0, 0};
  int sm[8]; float wm[8];
  #pragma unroll
  for (int q = 0; q < 8; ++q) {
    int idx = q;
    if (idx == 0)       { sm[q] = n; wm[q] = dd; }
    else if (idx < cnt) { int e = e0 + idx - 1; sm[q] = csr_src[e]; wm[q] = csr_norm[e]; }
    else                { sm[q] = n; wm[q] = 0.f; }
  }
  for (int i = 0; i < cnt; i += 8) {
    uint4 r0 = *reinterpret_cast<const uint4*>(G2h + (size_t)sm[0] * 512 + l * 8);
    uint4 r1 = *reinterpret_cast<const uint4*>(G2h + (size_t)sm[1] * 512 + l * 8);
    uint4 r2 = *reinterpret_cast<const uint4*>(G2h + (size_t)sm[2] * 512 + l * 8);
    uint4 r3 = *reinterpret_cast<const uint4*>(G2h + (size_t)sm[3] * 512 + l * 8);
    uint4 r4 = *reinterpret_cast<const uint4*>(G2h + (size_t)sm[4] * 512 + l * 8);
    uint4 r5 = *reinterpret_cast<const uint4*>(G2h + (size_t)sm[5] * 512 + l * 8);
    uint4 r6 = *reinterpret_cast<const uint4*>(G2h + (size_t)sm[6] * 512 + l * 8);
    uint4 r7 = *reinterpret_cast<const uint4*>(G2h + (size_t)sm[7] * 512 + l * 8);
    float w0 = wm[0], w1 = wm[1], w2 = wm[2], w3 = wm[3];
    float w4 = wm[4], w5 = wm[5], w6 = wm[6], w7 = wm[7];
    #pragma unroll
    for (int q = 0; q < 8; ++q) {
      int idx = i + 8 + q;           // >= 8, never self
      if (idx < cnt) { int e = e0 + idx - 1; sm[q] = csr_src[e]; wm[q] = csr_norm[e]; }
      else           { sm[q] = n; wm[q] = 0.f; }
    }
    accum8(acc, r0, w0);
    accum8(acc, r1, w1);
    accum8(acc, r2, w2);
    accum8(acc, r3, w3);
    accum8(acc, r4, w4);
    accum8(acc, r5, w5);
    accum8(acc, r6, w6);
    accum8(acc, r7, w7);
  }
  #pragma unroll
  for (int q = 0; q < 8; ++q)
    h2s[w][l * 8 + q] = fmaxf(acc[q] + b2[(l * 8 + q) & 63], 0.f);
  __syncthreads();
  // per-t dense: G3[t*64 + j] = sum_k h2[t*64+k] * W3[k][j]
  int t = tid >> 5;            // 0..7
  int jh = tid & 31, j0 = 2 * jh;
  float g[4][2];
  #pragma unroll
  for (int q = 0; q < 4; ++q) { g[q][0] = 0.f; g[q][1] = 0.f; }
  const float2* W3v = (const float2*)W3;
  for (int k = 0; k < 64; ++k) {
    float2 wv = W3v[k * 32 + jh];
    #pragma unroll
    for (int q = 0; q < 4; ++q) {
      float h = h2s[q][t * 64 + k];
      g[q][0] = fmaf(h, wv.x, g[q][0]);
      g[q][1] = fmaf(h, wv.y, g[q][1]);
    }
  }
  #pragma unroll
  for (int q = 0; q < 4; ++q) {
    __half2 hv;
    hv.x = __float2half_rn(g[q][0]);
    hv.y = __float2half_rn(g[q][1]);
    *reinterpret_cast<__half2*>(G3h + (size_t)(n0 + q) * 512 + t * 64 + j0) = hv;
  }
}

// ---------------- conv3 + head: aggregate G3h (8-deep); h3=relu(+b3); out = relu(h3@Wseq+bseq)@Wcls+bcls ----------------
__global__ void conv3w_kernel(const __half* __restrict__ G3h, const float* __restrict__ dinv,
                              const int* __restrict__ rowptr, const int* __restrict__ csr_src,
                              const float* __restrict__ csr_norm, const float* __restrict__ b3,
                              const float* __restrict__ Wseq, const float* __restrict__ bseq,
                              const float* __restrict__ Wcls, const float* __restrict__ bcls,
                              float* __restrict__ out) {
  __shared__ float h3s[4][512];
  __shared__ float red[4][4][64];
  __shared__ float hfs[4][64];
  int tid = threadIdx.x;
  int w = tid >> 6, l = tid & 63;
  int n0 = blockIdx.x * 4;
  int n = n0 + w;
  float di = dinv[n], dd = di * di;
  int e0 = rowptr[n], e1 = rowptr[n + 1];
  int cnt = e1 - e0 + 1;
  float acc[8] = {0, 0, 0, 0, 0, 0, 0, 0};
  int sm[8]; float wm[8];
  #pragma unroll
  for (int q = 0; q < 8; ++q) {
    int idx = q;
    if (idx == 0)       { sm[q] = n; wm[q] = dd; }
    else if (idx < cnt) { int e = e0 + idx - 1; sm[q] = csr_src[e]; wm[q] = csr_norm[e]; }
    else                { sm[q] = n; wm[q] = 0.f; }
  }
  for (int i = 0; i < cnt; i += 8) {
    uint4 r0 = *reinterpret_cast<const uint4*>(G3h + (size_t)sm[0] * 512 + l * 8);
    uint4 r1 = *reinterpret_cast<const uint4*>(G3h + (size_t)sm[1] * 512 + l * 8);
    uint4 r2 = *reinterpret_cast<const uint4*>(G3h + (size_t)sm[2] * 512 + l * 8);
    uint4 r3 = *reinterpret_cast<const uint4*>(G3h + (size_t)sm[3] * 512 + l * 8);
    uint4 r4 = *reinterpret_cast<const uint4*>(G3h + (size_t)sm[4] * 512 + l * 8);
    uint4 r5 = *reinterpret_cast<const uint4*>(G3h + (size_t)sm[5] * 512 + l * 8);
    uint4 r6 = *reinterpret_cast<const uint4*>(G3h + (size_t)sm[6] * 512 + l * 8);
    uint4 r7 = *reinterpret_cast<const uint4*>(G3h + (size_t)sm[7] * 512 + l * 8);
    float w0 = wm[0], w1 = wm[1], w2 = wm[2], w3 = wm[3];
    float w4 = wm[4], w5 = wm[5], w6 = wm[6], w7 = wm[7];
    #pragma unroll
    for (int q = 0; q < 8; ++q) {
      int idx = i + 8 + q;
      if (idx < cnt) { int e = e0 + idx - 1; sm[q] = csr_src[e]; wm[q] = csr_norm[e]; }
      else           { sm[q] = n; wm[q] = 0.f; }
    }
    accum8(acc, r0, w0);
    accum8(acc, r1, w1);
    accum8(acc, r2, w2);
    accum8(acc, r3, w3);
    accum8(acc, r4, w4);
    accum8(acc, r5, w5);
    accum8(acc, r6, w6);
    accum8(acc, r7, w7);
  }
  #pragma unroll
  for (int q = 0; q < 8; ++q)
    h3s[w][l * 8 + q] = fmaxf(acc[q] + b3[(l * 8 + q) & 63], 0.f);
  __syncthreads();
  // seq contraction: partial[p][nb][j] = sum_{c in p-range} h3[nb][c] * Wseq[c][j]
  int p = tid >> 6, j = tid & 63;
  float pa0 = 0.f, pa1 = 0.f, pa2 = 0.f, pa3 = 0.f;
  for (int ci = 0; ci < 128; ++ci) {
    int c = p * 128 + ci;
    float wv = Wseq[(size_t)c * 64 + j];
    pa0 = fmaf(h3s[0][c], wv, pa0);
    pa1 = fmaf(h3s[1][c], wv, pa1);
    pa2 = fmaf(h3s[2][c], wv, pa2);
    pa3 = fmaf(h3s[3][c], wv, pa3);
  }
  red[p][0][j] = pa0; red[p][1][j] = pa1; red[p][2][j] = pa2; red[p][3][j] = pa3;
  __syncthreads();
  int nb = tid >> 6, k = tid & 63;
  float s = red[0][nb][k] + red[1][nb][k] + red[2][nb][k] + red[3][nb][k] + bseq[k];
  hfs[nb][k] = fmaxf(s, 0.f);
  __syncthreads();
  if (k < C) {
    float o = bcls[k];
    #pragma unroll
    for (int kk = 0; kk < 64; ++kk) o = fmaf(hfs[nb][kk], Wcls[kk * C + k], o);
    out[(size_t)(n0 + nb) * C + k] = o;
  }
}

// ================= NARROW FALLBACK (fp32, per-t) =================
__global__ void layer1N_kernel(const float* __restrict__ xagg, const float* __restrict__ W1,
                               const float* __restrict__ b1, const float* __restrict__ W2,
                               float* __restrict__ GA, int t) {
  __shared__ float hs[4][H];
  int tid = threadIdx.x;
  int wv = tid >> 6, j = tid & 63;
  int n = blockIdx.x * 4 + wv;
  const float* xa = xagg + (size_t)n * 128;
  float a = b1[j];
  #pragma unroll
  for (int f = 0; f < 16; ++f) a += xa[f * 8 + t] * W1[f * H + j];
  hs[wv][j] = fmaxf(a, 0.f);
  __syncthreads();
  float g = 0.f;
  #pragma unroll
  for (int k = 0; k < H; ++k) g += hs[wv][k] * W2[k * H + j];
  GA[(size_t)n * H + j] = g;
}

template<bool ACCUM>
__global__ void convN_kernel(const float* __restrict__ Gin, const float* __restrict__ dinv,
                             const int* __restrict__ rowptr, const int* __restrict__ csr_src,
                             const float* __restrict__ csr_norm, const float* __restrict__ b,
                             const float* __restrict__ Wnext, float* __restrict__ Gout) {
  __shared__ __align__(16) float hs[4][H];
  int tid = threadIdx.x;
  int wv = tid >> 6, lane = tid & 63;
  int sub = lane >> 4, q = lane & 15;
  int n = blockIdx.x * 4 + wv;
  float di = dinv[n];
  const float4* G4 = (const float4*)Gin;
  float4 a0 = {0,0,0,0}, a1 = {0,0,0,0};
  int e0 = rowptr[n], e1 = rowptr[n + 1];
  int e = e0 + sub;
  for (; e + 4 < e1; e += 8) {
    int s0 = csr_src[e];     float w0 = csr_norm[e];
    int s1 = csr_src[e + 4]; float w1 = csr_norm[e + 4];
    float4 r0 = G4[(size_t)s0 * 16 + q];
    float4 r1 = G4[(size_t)s1 * 16 + q];
    a0.x += w0 * r0.x; a0.y += w0 * r0.y; a0.z += w0 * r0.z; a0.w += w0 * r0.w;
    a1.x += w1 * r1.x; a1.y += w1 * r1.y; a1.z += w1 * r1.z; a1.w += w1 * r1.w;
  }
  for (; e < e1; e += 4) {
    int s0 = csr_src[e]; float w0 = csr_norm[e];
    float4 r0 = G4[(size_t)s0 * 16 + q];
    a0.x += w0 * r0.x; a0.y += w0 * r0.y; a0.z += w0 * r0.z; a0.w += w0 * r0.w;
  }
  a0.x += a1.x; a0.y += a1.y; a0.z += a1.z; a0.w += a1.w;
  #pragma unroll
  for (int off = 16; off <= 32; off <<= 1) {
    a0.x += __shfl_xor(a0.x, off, 64);
    a0.y += __shfl_xor(a0.y, off, 64);
    a0.z += __shfl_xor(a0.z, off, 64);
    a0.w += __shfl_xor(a0.w, off, 64);
  }
  float4 own = G4[(size_t)n * 16 + q];
  float dd = di * di;
  if (sub == 0) {
    float4 h;
    h.x = fmaxf(a0.x + dd * own.x + b[4 * q + 0], 0.f);
    h.y = fmaxf(a0.y + dd * own.y + b[4 * q + 1], 0.f);
    h.z = fmaxf(a0.z + dd * own.z + b[4 * q + 2], 0.f);
    h.w = fmaxf(a0.w + dd * own.w + b[4 * q + 3], 0.f);
    ((float4*)hs[wv])[q] = h;
  }
  __syncthreads();
  float g = 0.f;
  #pragma unroll
  for (int k = 0; k < H; ++k) g += hs[wv][k] * Wnext[k * H + lane];
  if (ACCUM) Gout[(size_t)n * H + lane] += g;
  else       Gout[(size_t)n * H + lane]  = g;
}

__global__ void final_kernel(const float* __restrict__ acc, const float* __restrict__ bseq,
                             const float* __restrict__ Wcls, const float* __restrict__ bcls,
                             float* __restrict__ out) {
  __shared__ float hs[4][H];
  int tid = threadIdx.x;
  int wv = tid >> 6, j = tid & 63;
  int n = blockIdx.x * 4 + wv;
  hs[wv][j] = fmaxf(acc[(size_t)n * H + j] + bseq[j], 0.0f);
  __syncthreads();
  if (j < C) {
    float o = bcls[j];
    #pragma unroll
    for (int k = 0; k < H; ++k) o += hs[wv][k] * Wcls[k * C + j];
    out[(size_t)n * C + j] = o;
  }
}

extern "C" void kernel_launch(void* const* d_in, const int* in_sizes, int n_in,
                              void* d_out, int out_size, void* d_ws, size_t ws_size,
                              hipStream_t stream) {
  const float* x    = (const float*)d_in[0];
  const int*   ei   = (const int*)  d_in[1];
  const float* w    = (const float*)d_in[2];
  const float* W1   = (const float*)d_in[3];
  const float* b1   = (const float*)d_in[4];
  const float* W2   = (const float*)d_in[5];
  const float* b2   = (const float*)d_in[6];
  const float* W3   = (const float*)d_in[7];
  const float* b3   = (const float*)d_in[8];
  const float* Wseq = (const float*)d_in[9];
  const float* bseq = (const float*)d_in[10];
  const float* Wcls = (const float*)d_in[11];
  const float* bcls = (const float*)d_in[12];
  float* out = (float*)d_out;

  char* p = (char*)d_ws;
  auto alloc = [&](size_t bytes) -> char* {
    char* r = p; p += (bytes + 255) & ~(size_t)255; return r;
  };
  float*  deg     = (float*) alloc((size_t)N * 4);      // becomes dinv
  int*    counts  = (int*)   alloc((size_t)N * 4);
  int*    fillc   = (int*)   alloc((size_t)N * 4);
  int*    rowptr  = (int*)   alloc((size_t)(N + 1) * 4);
  int*    bsum    = (int*)   alloc(64 * 4);
  int*    boff    = (int*)   alloc(64 * 4);
  int*    csr_src = (int*)   alloc((size_t)E * 4);
  float*  csr_nrm = (float*) alloc((size_t)E * 4);
  float*  xagg    = (float*) alloc((size_t)N * 128 * 4);
  __half* xh      = (__half*)alloc((size_t)N * 128 * 2);

  hipMemsetAsync(deg,    0, (size_t)N * 4, stream);
  hipMemsetAsync(counts, 0, (size_t)N * 4, stream);
  hipMemsetAsync(fillc,  0, (size_t)N * 4, stream);

  constexpr int NTILES = (N + 1023) / 1024;   // 49
  cvt_x_kernel<<<(N * 32 + 255) / 256, 256, 0, stream>>>(x, xh);
  deg_count_kernel<<<(E + 255) / 256, 256, 0, stream>>>(ei, w, deg, counts);
  dinv_kernel<<<(N + 255) / 256, 256, 0, stream>>>(deg);
  scanA_kernel<<<NTILES, 256, 0, stream>>>(counts, rowptr, bsum);
  scanB_kernel<<<1, 64, 0, stream>>>(bsum, boff, NTILES);
  scanC_kernel<<<(N + 255) / 256, 256, 0, stream>>>(rowptr, boff);
  fill_kernel<<<(E + 255) / 256, 256, 0, stream>>>(ei, w, deg, rowptr, fillc, csr_src, csr_nrm);
  agg_x_kernel<<<N / 4, 256, 0, stream>>>(xh, deg, rowptr, csr_src, csr_nrm, xagg);

  // wide needs: common ~52MB + G2h 51.2MB + G3h 51.2MB ~= 155MB
  bool wide = ws_size >= (size_t)155 * 1000 * 1000;

  if (wide) {
    __half* G2h = (__half*)alloc((size_t)N * 512 * 2);
    __half* G3h = (__half*)alloc((size_t)N * 512 * 2);
    dense12_kernel<<<N / 4, 256, 0, stream>>>(xagg, W1, b1, W2, G2h);
    conv2w_kernel<<<N / 4, 256, 0, stream>>>(G2h, deg, rowptr, csr_src, csr_nrm, b2, W3, G3h);
    conv3w_kernel<<<N / 4, 256, 0, stream>>>(G3h, deg, rowptr, csr_src, csr_nrm, b3,
                                             Wseq, bseq, Wcls, bcls, out);
  } else {
    float* GA  = (float*)alloc((size_t)N * H * 4);
    float* GB  = (float*)alloc((size_t)N * H * 4);
    float* acc = (float*)alloc((size_t)N * H * 4);
    hipMemsetAsync(acc, 0, (size_t)N * H * 4, stream);
    for (int t = 0; t < T; ++t) {
      layer1N_kernel<<<N / 4, 256, 0, stream>>>(xagg, W1, b1, W2, GA, t);
      convN_kernel<false><<<N / 4, 256, 0, stream>>>(GA, deg, rowptr, csr_src, csr_nrm, b2, W3, GB);
      convN_kernel<true ><<<N / 4, 256, 0, stream>>>(GB, deg, rowptr, csr_src, csr_nrm, b3,
                                                     Wseq + (size_t)t * H * H, acc);
    }
    final_kernel<<<N / 4, 256, 0, stream>>>(acc, bseq, Wcls, bcls, out);
  }
}

// Round 10
// 835.448 us; speedup vs baseline: 1.0316x; 1.0257x over previous
//
#include <hip/hip_runtime.h>
#include <hip/hip_fp16.h>

constexpr int N  = 50000;
constexpr int E  = 1600000;
constexpr int T  = 8;
constexpr int H  = 64;
constexpr int C  = 10;

// ---------------- degree + histogram ----------------
__global__ void deg_count_kernel(const int* __restrict__ ei, const float* __restrict__ w,
                                 float* __restrict__ deg, int* __restrict__ counts) {
  int e = blockIdx.x * blockDim.x + threadIdx.x;
  if (e >= E) return;
  int d = ei[E + e];
  atomicAdd(&deg[d], w[e]);
  atomicAdd(&counts[d], 1);
}

__global__ void dinv_kernel(float* deg) {
  int n = blockIdx.x * blockDim.x + threadIdx.x;
  if (n >= N) return;
  deg[n] = rsqrtf(deg[n] + 1.0f);  // +1 = self-loop weight
}

// ---------------- two-level scan: A (per-1024-tile), B (tile sums), C (add offsets) ----------------
__global__ void scanA_kernel(const int* __restrict__ counts, int* __restrict__ rowptr,
                             int* __restrict__ bsum) {
  __shared__ int ws[4];
  int b = blockIdx.x, t = threadIdx.x;
  int base = b * 1024 + t * 4;
  int v0 = (base + 0 < N) ? counts[base + 0] : 0;
  int v1 = (base + 1 < N) ? counts[base + 1] : 0;
  int v2 = (base + 2 < N) ? counts[base + 2] : 0;
  int v3 = (base + 3 < N) ? counts[base + 3] : 0;
  int s = v0 + v1 + v2 + v3;
  int lane = t & 63, wid = t >> 6;
  int x = s;
  #pragma unroll
  for (int off = 1; off < 64; off <<= 1) {
    int y = __shfl_up(x, off, 64);
    if (lane >= off) x += y;
  }
  if (lane == 63) ws[wid] = x;
  __syncthreads();
  int woff = 0;
  #pragma unroll
  for (int k = 0; k < 4; ++k) if (k < wid) woff += ws[k];
  int a = x + woff - s;   // exclusive prefix within tile
  a += v0; if (base + 0 < N) rowptr[base + 1] = a;
  a += v1; if (base + 1 < N) rowptr[base + 2] = a;
  a += v2; if (base + 2 < N) rowptr[base + 3] = a;
  a += v3; if (base + 3 < N) rowptr[base + 4] = a;
  if (t == 255) bsum[b] = x + woff;   // tile total
}

__global__ void scanB_kernel(const int* __restrict__ bsum, int* __restrict__ boff, int nb) {
  int t = threadIdx.x;   // 64 threads
  int v = (t < nb) ? bsum[t] : 0;
  int x = v;
  #pragma unroll
  for (int off = 1; off < 64; off <<= 1) {
    int y = __shfl_up(x, off, 64);
    if (t >= off) x += y;
  }
  if (t < nb) boff[t] = x - v;   // exclusive
}

__global__ void scanC_kernel(int* __restrict__ rowptr, const int* __restrict__ boff) {
  int i = blockIdx.x * 256 + threadIdx.x;
  if (i == 0) rowptr[0] = 0;
  if (i < N) rowptr[i + 1] += boff[i >> 10];
}

// ---------------- CSR fill (split arrays — wave-uniform scalar loads in gathers) ----------------
__global__ void fill_kernel(const int* __restrict__ ei, const float* __restrict__ w,
                            const float* __restrict__ dinv, const int* __restrict__ rowptr,
                            int* __restrict__ fill, int* __restrict__ csr_src,
                            float* __restrict__ csr_norm) {
  int e = blockIdx.x * blockDim.x + threadIdx.x;
  if (e >= E) return;
  int s = ei[e], d = ei[E + e];
  int pos = rowptr[d] + atomicAdd(&fill[d], 1);
  csr_src[pos] = s;
  csr_norm[pos] = dinv[s] * w[e] * dinv[d];
}

// ---------------- x (fp32) -> xh (fp16) ----------------
__global__ void cvt_x_kernel(const float* __restrict__ x, __half* __restrict__ xh) {
  int i = blockIdx.x * blockDim.x + threadIdx.x;  // over N*32 float4s
  if (i >= N * 32) return;
  float4 v = ((const float4*)x)[i];
  __half2 h0; h0.x = __float2half_rn(v.x); h0.y = __float2half_rn(v.y);
  __half2 h1; h1.x = __float2half_rn(v.z); h1.y = __float2half_rn(v.w);
  uint2 u;
  u.x = __builtin_bit_cast(unsigned int, h0);
  u.y = __builtin_bit_cast(unsigned int, h1);
  ((uint2*)xh)[i] = u;
}

// 8-halves fused accumulate helper
__device__ __forceinline__ void accum8(float* acc, uint4 r, float wgt) {
  float2 f0 = __half22float2(__builtin_bit_cast(__half2, r.x));
  float2 f1 = __half22float2(__builtin_bit_cast(__half2, r.y));
  float2 f2 = __half22float2(__builtin_bit_cast(__half2, r.z));
  float2 f3 = __half22float2(__builtin_bit_cast(__half2, r.w));
  acc[0] = fmaf(wgt, f0.x, acc[0]); acc[1] = fmaf(wgt, f0.y, acc[1]);
  acc[2] = fmaf(wgt, f1.x, acc[2]); acc[3] = fmaf(wgt, f1.y, acc[3]);
  acc[4] = fmaf(wgt, f2.x, acc[4]); acc[5] = fmaf(wgt, f2.y, acc[5]);
  acc[6] = fmaf(wgt, f3.x, acc[6]); acc[7] = fmaf(wgt, f3.y, acc[7]);
}

// ---------------- xagg = Ahat @ X, fp16 256B rows; 4 groups x 2-deep = 8 rows in flight ----------------
__global__ void agg_x_kernel(const __half* __restrict__ xh, const float* __restrict__ dinv,
                             const int* __restrict__ rowptr, const int* __restrict__ csr_src,
                             const float* __restrict__ csr_norm, float* __restrict__ xagg) {
  int tid = threadIdx.x;
  int w = tid >> 6, l = tid & 63;
  int sub = l >> 4, q = l & 15;      // 4 groups x 16 lanes; lane covers 16B of 256B row
  int n = blockIdx.x * 4 + w;
  float di = dinv[n], dd = di * di;
  int e0 = rowptr[n], e1 = rowptr[n + 1];
  int cnt = e1 - e0 + 1;             // item 0 = self
  float acc[8] = {0, 0, 0, 0, 0, 0, 0, 0};
  int sA, sB; float wA, wB;
  auto meta = [&](int idx, int& s_, float& w_) {
    if (idx == 0)       { s_ = n; w_ = dd; }
    else if (idx < cnt) { s_ = csr_src[e0 + idx - 1]; w_ = csr_norm[e0 + idx - 1]; }
    else                { s_ = n; w_ = 0.f; }
  };
  meta(sub,     sA, wA);
  meta(sub + 4, sB, wB);
  for (int i = sub; i < cnt; i += 8) {
    uint4 rA = *reinterpret_cast<const uint4*>(xh + (size_t)sA * 128 + q * 8);
    uint4 rB = *reinterpret_cast<const uint4*>(xh + (size_t)sB * 128 + q * 8);
    float uA = wA, uB = wB;
    meta(i + 8,  sA, wA);
    meta(i + 12, sB, wB);
    accum8(acc, rA, uA);
    accum8(acc, rB, uB);
  }
  #pragma unroll
  for (int v = 0; v < 8; ++v) {
    acc[v] += __shfl_xor(acc[v], 16, 64);
    acc[v] += __shfl_xor(acc[v], 32, 64);
  }
  if (sub == 0) {
    float4 o0; o0.x = acc[0]; o0.y = acc[1]; o0.z = acc[2]; o0.w = acc[3];
    float4 o1; o1.x = acc[4]; o1.y = acc[5]; o1.z = acc[6]; o1.w = acc[7];
    float4* dst = (float4*)(xagg + (size_t)n * 128 + q * 8);
    dst[0] = o0; dst[1] = o1;
  }
}

// ---------------- dense: h1 = relu(xagg_t @ W1 + b1); G2 = h1 @ W2 (fp16, all t) ----------------
__global__ void dense12_kernel(const float* __restrict__ xagg, const float* __restrict__ W1,
                               const float* __restrict__ b1, const float* __restrict__ W2,
                               __half* __restrict__ G2h) {
  __shared__ float xs[4 * 128];
  __shared__ float h1s[4][8][64];
  int tid = threadIdx.x;
  int n0 = blockIdx.x * 4;
  ((float2*)xs)[tid] = ((const float2*)(xagg + (size_t)n0 * 128))[tid];
  __syncthreads();
  int nb = tid >> 6, j = tid & 63;
  float a[8];
  float bj = b1[j];
  #pragma unroll
  for (int t = 0; t < 8; ++t) a[t] = bj;
  for (int f = 0; f < 16; ++f) {
    float wv = W1[f * 64 + j];
    #pragma unroll
    for (int t = 0; t < 8; ++t) a[t] = fmaf(xs[nb * 128 + f * 8 + t], wv, a[t]);
  }
  #pragma unroll
  for (int t = 0; t < 8; ++t) h1s[nb][t][j] = fmaxf(a[t], 0.f);
  __syncthreads();
  float g[8];
  #pragma unroll
  for (int t = 0; t < 8; ++t) g[t] = 0.f;
  for (int k = 0; k < 64; ++k) {
    float wv = W2[k * 64 + j];
    #pragma unroll
    for (int t = 0; t < 8; ++t) g[t] = fmaf(h1s[nb][t][k], wv, g[t]);
  }
  __half* gp = G2h + (size_t)(n0 + nb) * 512 + j;
  #pragma unroll
  for (int t = 0; t < 8; ++t) gp[t * 64] = __float2half_rn(g[t]);
}

// ---------------- conv2: aggregate G2h (1KB fp16 rows, 4-deep); h2=relu(+b2); G3h = h2 @ W3 ----------------
__global__ void conv2w_kernel(const __half* __restrict__ G2h, const float* __restrict__ dinv,
                              const int* __restrict__ rowptr, const int* __restrict__ csr_src,
                              const float* __restrict__ csr_norm, const float* __restrict__ b2,
                              const float* __restrict__ W3, __half* __restrict__ G3h) {
  __shared__ float h2s[4][512];
  int tid = threadIdx.x;
  int w = tid >> 6, l = tid & 63;
  int n0 = blockIdx.x * 4;
  int n = n0 + w;
  float di = dinv[n], dd = di * di;
  int e0 = rowptr[n], e1 = rowptr[n + 1];
  int cnt = e1 - e0 + 1;             // item 0 = self
  float acc[8] = {0, 0, 0, 0, 0, 0, 0, 0};
  int sm[4]; float wm[4];
  #pragma unroll
  for (int q = 0; q < 4; ++q) {
    int idx = q;
    if (idx == 0)       { sm[q] = n; wm[q] = dd; }
    else if (idx < cnt) { int e = e0 + idx - 1; sm[q] = csr_src[e]; wm[q] = csr_norm[e]; }
    else                { sm[q] = n; wm[q] = 0.f; }
  }
  for (int i = 0; i < cnt; i += 4) {
    uint4 r0 = *reinterpret_cast<const uint4*>(G2h + (size_t)sm[0] * 512 + l * 8);
    uint4 r1 = *reinterpret_cast<const uint4*>(G2h + (size_t)sm[1] * 512 + l * 8);
    uint4 r2 = *reinterpret_cast<const uint4*>(G2h + (size_t)sm[2] * 512 + l * 8);
    uint4 r3 = *reinterpret_cast<const uint4*>(G2h + (size_t)sm[3] * 512 + l * 8);
    float w0 = wm[0], w1 = wm[1], w2 = wm[2], w3 = wm[3];
    #pragma unroll
    for (int q = 0; q < 4; ++q) {
      int idx = i + 4 + q;           // >= 4, never self
      if (idx < cnt) { int e = e0 + idx - 1; sm[q] = csr_src[e]; wm[q] = csr_norm[e]; }
      else           { sm[q] = n; wm[q] = 0.f; }
    }
    accum8(acc, r0, w0);
    accum8(acc, r1, w1);
    accum8(acc, r2, w2);
    accum8(acc, r3, w3);
  }
  #pragma unroll
  for (int q = 0; q < 8; ++q)
    h2s[w][l * 8 + q] = fmaxf(acc[q] + b2[(l * 8 + q) & 63], 0.f);
  __syncthreads();
  // per-t dense: G3[t*64 + j] = sum_k h2[t*64+k] * W3[k][j]
  int t = tid >> 5;            // 0..7
  int jh = tid & 31, j0 = 2 * jh;
  float g[4][2];
  #pragma unroll
  for (int q = 0; q < 4; ++q) { g[q][0] = 0.f; g[q][1] = 0.f; }
  const float2* W3v = (const float2*)W3;
  for (int k = 0; k < 64; ++k) {
    float2 wv = W3v[k * 32 + jh];
    #pragma unroll
    for (int q = 0; q < 4; ++q) {
      float h = h2s[q][t * 64 + k];
      g[q][0] = fmaf(h, wv.x, g[q][0]);
      g[q][1] = fmaf(h, wv.y, g[q][1]);
    }
  }
  #pragma unroll
  for (int q = 0; q < 4; ++q) {
    __half2 hv;
    hv.x = __float2half_rn(g[q][0]);
    hv.y = __float2half_rn(g[q][1]);
    *reinterpret_cast<__half2*>(G3h + (size_t)(n0 + q) * 512 + t * 64 + j0) = hv;
  }
}

// ---------------- conv3 + head: aggregate G3h (4-deep); h3=relu(+b3); out = relu(h3@Wseq+bseq)@Wcls+bcls ----------------
__global__ void conv3w_kernel(const __half* __restrict__ G3h, const float* __restrict__ dinv,
                              const int* __restrict__ rowptr, const int* __restrict__ csr_src,
                              const float* __restrict__ csr_norm, const float* __restrict__ b3,
                              const float* __restrict__ Wseq, const float* __restrict__ bseq,
                              const float* __restrict__ Wcls, const float* __restrict__ bcls,
                              float* __restrict__ out) {
  __shared__ float h3s[4][512];
  __shared__ float red[4][4][64];
  __shared__ float hfs[4][64];
  int tid = threadIdx.x;
  int w = tid >> 6, l = tid & 63;
  int n0 = blockIdx.x * 4;
  int n = n0 + w;
  float di = dinv[n], dd = di * di;
  int e0 = rowptr[n], e1 = rowptr[n + 1];
  int cnt = e1 - e0 + 1;
  float acc[8] = {0, 0, 0, 0, 0, 0, 0, 0};
  int sm[4]; float wm[4];
  #pragma unroll
  for (int q = 0; q < 4; ++q) {
    int idx = q;
    if (idx == 0)       { sm[q] = n; wm[q] = dd; }
    else if (idx < cnt) { int e = e0 + idx - 1; sm[q] = csr_src[e]; wm[q] = csr_norm[e]; }
    else                { sm[q] = n; wm[q] = 0.f; }
  }
  for (int i = 0; i < cnt; i += 4) {
    uint4 r0 = *reinterpret_cast<const uint4*>(G3h + (size_t)sm[0] * 512 + l * 8);
    uint4 r1 = *reinterpret_cast<const uint4*>(G3h + (size_t)sm[1] * 512 + l * 8);
    uint4 r2 = *reinterpret_cast<const uint4*>(G3h + (size_t)sm[2] * 512 + l * 8);
    uint4 r3 = *reinterpret_cast<const uint4*>(G3h + (size_t)sm[3] * 512 + l * 8);
    float w0 = wm[0], w1 = wm[1], w2 = wm[2], w3 = wm[3];
    #pragma unroll
    for (int q = 0; q < 4; ++q) {
      int idx = i + 4 + q;
      if (idx < cnt) { int e = e0 + idx - 1; sm[q] = csr_src[e]; wm[q] = csr_norm[e]; }
      else           { sm[q] = n; wm[q] = 0.f; }
    }
    accum8(acc, r0, w0);
    accum8(acc, r1, w1);
    accum8(acc, r2, w2);
    accum8(acc, r3, w3);
  }
  #pragma unroll
  for (int q = 0; q < 8; ++q)
    h3s[w][l * 8 + q] = fmaxf(acc[q] + b3[(l * 8 + q) & 63], 0.f);
  __syncthreads();
  // seq contraction: partial[p][nb][j] = sum_{c in p-range} h3[nb][c] * Wseq[c][j]
  int p = tid >> 6, j = tid & 63;
  float pa0 = 0.f, pa1 = 0.f, pa2 = 0.f, pa3 = 0.f;
  for (int ci = 0; ci < 128; ++ci) {
    int c = p * 128 + ci;
    float wv = Wseq[(size_t)c * 64 + j];
    pa0 = fmaf(h3s[0][c], wv, pa0);
    pa1 = fmaf(h3s[1][c], wv, pa1);
    pa2 = fmaf(h3s[2][c], wv, pa2);
    pa3 = fmaf(h3s[3][c], wv, pa3);
  }
  red[p][0][j] = pa0; red[p][1][j] = pa1; red[p][2][j] = pa2; red[p][3][j] = pa3;
  __syncthreads();
  int nb = tid >> 6, k = tid & 63;
  float s = red[0][nb][k] + red[1][nb][k] + red[2][nb][k] + red[3][nb][k] + bseq[k];
  hfs[nb][k] = fmaxf(s, 0.f);
  __syncthreads();
  if (k < C) {
    float o = bcls[k];
    #pragma unroll
    for (int kk = 0; kk < 64; ++kk) o = fmaf(hfs[nb][kk], Wcls[kk * C + k], o);
    out[(size_t)(n0 + nb) * C + k] = o;
  }
}

// ================= NARROW FALLBACK (fp32, per-t) =================
__global__ void layer1N_kernel(const float* __restrict__ xagg, const float* __restrict__ W1,
                               const float* __restrict__ b1, const float* __restrict__ W2,
                               float* __restrict__ GA, int t) {
  __shared__ float hs[4][H];
  int tid = threadIdx.x;
  int wv = tid >> 6, j = tid & 63;
  int n = blockIdx.x * 4 + wv;
  const float* xa = xagg + (size_t)n * 128;
  float a = b1[j];
  #pragma unroll
  for (int f = 0; f < 16; ++f) a += xa[f * 8 + t] * W1[f * H + j];
  hs[wv][j] = fmaxf(a, 0.f);
  __syncthreads();
  float g = 0.f;
  #pragma unroll
  for (int k = 0; k < H; ++k) g += hs[wv][k] * W2[k * H + j];
  GA[(size_t)n * H + j] = g;
}

template<bool ACCUM>
__global__ void convN_kernel(const float* __restrict__ Gin, const float* __restrict__ dinv,
                             const int* __restrict__ rowptr, const int* __restrict__ csr_src,
                             const float* __restrict__ csr_norm, const float* __restrict__ b,
                             const float* __restrict__ Wnext, float* __restrict__ Gout) {
  __shared__ __align__(16) float hs[4][H];
  int tid = threadIdx.x;
  int wv = tid >> 6, lane = tid & 63;
  int sub = lane >> 4, q = lane & 15;
  int n = blockIdx.x * 4 + wv;
  float di = dinv[n];
  const float4* G4 = (const float4*)Gin;
  float4 a0 = {0,0,0,0}, a1 = {0,0,0,0};
  int e0 = rowptr[n], e1 = rowptr[n + 1];
  int e = e0 + sub;
  for (; e + 4 < e1; e += 8) {
    int s0 = csr_src[e];     float w0 = csr_norm[e];
    int s1 = csr_src[e + 4]; float w1 = csr_norm[e + 4];
    float4 r0 = G4[(size_t)s0 * 16 + q];
    float4 r1 = G4[(size_t)s1 * 16 + q];
    a0.x += w0 * r0.x; a0.y += w0 * r0.y; a0.z += w0 * r0.z; a0.w += w0 * r0.w;
    a1.x += w1 * r1.x; a1.y += w1 * r1.y; a1.z += w1 * r1.z; a1.w += w1 * r1.w;
  }
  for (; e < e1; e += 4) {
    int s0 = csr_src[e]; float w0 = csr_norm[e];
    float4 r0 = G4[(size_t)s0 * 16 + q];
    a0.x += w0 * r0.x; a0.y += w0 * r0.y; a0.z += w0 * r0.z; a0.w += w0 * r0.w;
  }
  a0.x += a1.x; a0.y += a1.y; a0.z += a1.z; a0.w += a1.w;
  #pragma unroll
  for (int off = 16; off <= 32; off <<= 1) {
    a0.x += __shfl_xor(a0.x, off, 64);
    a0.y += __shfl_xor(a0.y, off, 64);
    a0.z += __shfl_xor(a0.z, off, 64);
    a0.w += __shfl_xor(a0.w, off, 64);
  }
  float4 own = G4[(size_t)n * 16 + q];
  float dd = di * di;
  if (sub == 0) {
    float4 h;
    h.x = fmaxf(a0.x + dd * own.x + b[4 * q + 0], 0.f);
    h.y = fmaxf(a0.y + dd * own.y + b[4 * q + 1], 0.f);
    h.z = fmaxf(a0.z + dd * own.z + b[4 * q + 2], 0.f);
    h.w = fmaxf(a0.w + dd * own.w + b[4 * q + 3], 0.f);
    ((float4*)hs[wv])[q] = h;
  }
  __syncthreads();
  float g = 0.f;
  #pragma unroll
  for (int k = 0; k < H; ++k) g += hs[wv][k] * Wnext[k * H + lane];
  if (ACCUM) Gout[(size_t)n * H + lane] += g;
  else       Gout[(size_t)n * H + lane]  = g;
}

__global__ void final_kernel(const float* __restrict__ acc, const float* __restrict__ bseq,
                             const float* __restrict__ Wcls, const float* __restrict__ bcls,
                             float* __restrict__ out) {
  __shared__ float hs[4][H];
  int tid = threadIdx.x;
  int wv = tid >> 6, j = tid & 63;
  int n = blockIdx.x * 4 + wv;
  hs[wv][j] = fmaxf(acc[(size_t)n * H + j] + bseq[j], 0.0f);
  __syncthreads();
  if (j < C) {
    float o = bcls[j];
    #pragma unroll
    for (int k = 0; k < H; ++k) o += hs[wv][k] * Wcls[k * C + j];
    out[(size_t)n * C + j] = o;
  }
}

extern "C" void kernel_launch(void* const* d_in, const int* in_sizes, int n_in,
                              void* d_out, int out_size, void* d_ws, size_t ws_size,
                              hipStream_t stream) {
  const float* x    = (const float*)d_in[0];
  const int*   ei   = (const int*)  d_in[1];
  const float* w    = (const float*)d_in[2];
  const float* W1   = (const float*)d_in[3];
  const float* b1   = (const float*)d_in[4];
  const float* W2   = (const float*)d_in[5];
  const float* b2   = (const float*)d_in[6];
  const float* W3   = (const float*)d_in[7];
  const float* b3   = (const float*)d_in[8];
  const float* Wseq = (const float*)d_in[9];
  const float* bseq = (const float*)d_in[10];
  const float* Wcls = (const float*)d_in[11];
  const float* bcls = (const float*)d_in[12];
  float* out = (float*)d_out;

  char* p = (char*)d_ws;
  auto alloc = [&](size_t bytes) -> char* {
    char* r = p; p += (bytes + 255) & ~(size_t)255; return r;
  };
  float*  deg     = (float*) alloc((size_t)N * 4);      // becomes dinv
  int*    counts  = (int*)   alloc((size_t)N * 4);
  int*    fillc   = (int*)   alloc((size_t)N * 4);
  int*    rowptr  = (int*)   alloc((size_t)(N + 1) * 4);
  int*    bsum    = (int*)   alloc(64 * 4);
  int*    boff    = (int*)   alloc(64 * 4);
  int*    csr_src = (int*)   alloc((size_t)E * 4);
  float*  csr_nrm = (float*) alloc((size_t)E * 4);
  float*  xagg    = (float*) alloc((size_t)N * 128 * 4);
  __half* xh      = (__half*)alloc((size_t)N * 128 * 2);

  hipMemsetAsync(deg,    0, (size_t)N * 4, stream);
  hipMemsetAsync(counts, 0, (size_t)N * 4, stream);
  hipMemsetAsync(fillc,  0, (size_t)N * 4, stream);

  constexpr int NTILES = (N + 1023) / 1024;   // 49
  cvt_x_kernel<<<(N * 32 + 255) / 256, 256, 0, stream>>>(x, xh);
  deg_count_kernel<<<(E + 255) / 256, 256, 0, stream>>>(ei, w, deg, counts);
  dinv_kernel<<<(N + 255) / 256, 256, 0, stream>>>(deg);
  scanA_kernel<<<NTILES, 256, 0, stream>>>(counts, rowptr, bsum);
  scanB_kernel<<<1, 64, 0, stream>>>(bsum, boff, NTILES);
  scanC_kernel<<<(N + 255) / 256, 256, 0, stream>>>(rowptr, boff);
  fill_kernel<<<(E + 255) / 256, 256, 0, stream>>>(ei, w, deg, rowptr, fillc, csr_src, csr_nrm);
  agg_x_kernel<<<N / 4, 256, 0, stream>>>(xh, deg, rowptr, csr_src, csr_nrm, xagg);

  // wide needs: common ~52MB + G2h 51.2MB + G3h 51.2MB ~= 155MB
  bool wide = ws_size >= (size_t)155 * 1000 * 1000;

  if (wide) {
    __half* G2h = (__half*)alloc((size_t)N * 512 * 2);
    __half* G3h = (__half*)alloc((size_t)N * 512 * 2);
    dense12_kernel<<<N / 4, 256, 0, stream>>>(xagg, W1, b1, W2, G2h);
    conv2w_kernel<<<N / 4, 256, 0, stream>>>(G2h, deg, rowptr, csr_src, csr_nrm, b2, W3, G3h);
    conv3w_kernel<<<N / 4, 256, 0, stream>>>(G3h, deg, rowptr, csr_src, csr_nrm, b3,
                                             Wseq, bseq, Wcls, bcls, out);
  } else {
    float* GA  = (float*)alloc((size_t)N * H * 4);
    float* GB  = (float*)alloc((size_t)N * H * 4);
    float* acc = (float*)alloc((size_t)N * H * 4);
    hipMemsetAsync(acc, 0, (size_t)N * H * 4, stream);
    for (int t = 0; t < T; ++t) {
      layer1N_kernel<<<N / 4, 256, 0, stream>>>(xagg, W1, b1, W2, GA, t);
      convN_kernel<false><<<N / 4, 256, 0, stream>>>(GA, deg, rowptr, csr_src, csr_nrm, b2, W3, GB);
      convN_kernel<true ><<<N / 4, 256, 0, stream>>>(GB, deg, rowptr, csr_src, csr_nrm, b3,
                                                     Wseq + (size_t)t * H * H, acc);
    }
    final_kernel<<<N / 4, 256, 0, stream>>>(acc, bseq, Wcls, bcls, out);
  }
}